// Round 13
// baseline (510.853 us; speedup 1.0000x reference)
//
#include <hip/hip_runtime.h>
#include <hip/hip_bf16.h>

#define B_N 16384
#define D_N 512
#define K_N 2048

typedef __attribute__((ext_vector_type(8))) short bf16x8;
typedef __attribute__((ext_vector_type(4))) float f32x4;
typedef __attribute__((ext_vector_type(4))) unsigned short u16x4;
typedef unsigned short u16;

__device__ __forceinline__ float bf2f(short s) {
  return __builtin_bit_cast(float, ((unsigned)(u16)s) << 16);
}
__device__ __forceinline__ u16 f2bf(float x) {
  return __builtin_bit_cast(u16, __float2bfloat16(x));
}
__device__ __forceinline__ unsigned fbits(float x) {
  return __builtin_bit_cast(unsigned, x);
}
__device__ __forceinline__ float wred_sum(float v) {
#pragma unroll
  for (int o = 32; o; o >>= 1) v += __shfl_down(v, o, 64);
  return v;
}

__device__ __forceinline__ void gld16(const u16* g, const u16* l) {
  __builtin_amdgcn_global_load_lds((const __attribute__((address_space(1))) void*)g,
                                   (__attribute__((address_space(3))) void*)l, 16, 0, 0);
}

// ---------------- row l2norm + bf16 convert (normalized + raw) ----------------
__global__ __launch_bounds__(256) void k_rownorm(const float* __restrict__ z1,
                                                 const float* __restrict__ z2,
                                                 u16* __restrict__ zn1, u16* __restrict__ zn2,
                                                 u16* __restrict__ zb1, u16* __restrict__ zb2) {
  int wid = threadIdx.x >> 6, lane = threadIdx.x & 63;
  int row = blockIdx.x * 4 + wid;
  const float* z; u16 *zn, *zb; int r;
  if (row < B_N) { z = z1; zn = zn1; zb = zb1; r = row; }
  else { z = z2; zn = zn2; zb = zb2; r = row - B_N; }
  const float4* zr = (const float4*)(z + (size_t)r * D_N);
  float4 va = zr[lane], vb = zr[lane + 64];
  float ss = va.x*va.x + va.y*va.y + va.z*va.z + va.w*va.w
           + vb.x*vb.x + vb.y*vb.y + vb.z*vb.z + vb.w*vb.w;
#pragma unroll
  for (int o = 32; o; o >>= 1) ss += __shfl_xor(ss, o, 64);
  float inv = 1.0f / fmaxf(sqrtf(ss), 1e-12f);
  u16x4 pa = {f2bf(va.x), f2bf(va.y), f2bf(va.z), f2bf(va.w)};
  u16x4 pb = {f2bf(vb.x), f2bf(vb.y), f2bf(vb.z), f2bf(vb.w)};
  u16x4 na = {f2bf(va.x*inv), f2bf(va.y*inv), f2bf(va.z*inv), f2bf(va.w*inv)};
  u16x4 nb = {f2bf(vb.x*inv), f2bf(vb.y*inv), f2bf(vb.z*inv), f2bf(vb.w*inv)};
  ((u16x4*)(zb + (size_t)r * D_N))[lane] = pa;
  ((u16x4*)(zb + (size_t)r * D_N))[lane + 64] = pb;
  ((u16x4*)(zn + (size_t)r * D_N))[lane] = na;
  ((u16x4*)(zn + (size_t)r * D_N))[lane + 64] = nb;
}

// ---------------- W -> bf16 ----------------
__global__ __launch_bounds__(256) void k_convW(const float* __restrict__ W,
                                               u16* __restrict__ Wb) {
  size_t base = ((size_t)blockIdx.x * 256 + threadIdx.x) * 8;
#pragma unroll
  for (int j = 0; j < 8; j++) Wb[base + j] = f2bf(W[base + j]);
}

// ---------------- per-column sum / sumsq (bf16 input) ----------------
__global__ __launch_bounds__(512) void k_colstats(const u16* __restrict__ zb1,
                                                  const u16* __restrict__ zb2,
                                                  float* __restrict__ csum,
                                                  float* __restrict__ csumsq) {
  int zi = blockIdx.z;
  const u16* z = zi ? zb2 : zb1;
  __shared__ float s1[512], s2[512];
  int t = threadIdx.y * 64 + threadIdx.x;
  s1[t] = 0.f; s2[t] = 0.f;
  __syncthreads();
  int c0 = threadIdx.x * 8;
  float a[8], a2[8];
#pragma unroll
  for (int e = 0; e < 8; e++) { a[e] = 0.f; a2[e] = 0.f; }
  for (int u = 0; u < 16; u++) {
    int r = blockIdx.y * 128 + threadIdx.y + 8 * u;
    bf16x8 v = *(const bf16x8*)&z[(size_t)r * D_N + c0];
#pragma unroll
    for (int e = 0; e < 8; e++) { float x = bf2f(v[e]); a[e] += x; a2[e] += x * x; }
  }
#pragma unroll
  for (int e = 0; e < 8; e++) {
    atomicAdd(&s1[c0 + e], a[e]);
    atomicAdd(&s2[c0 + e], a2[e]);
  }
  __syncthreads();
  atomicAdd(&csum[zi * D_N + t], s1[t]);
  atomicAdd(&csumsq[zi * D_N + t], s2[t]);
}

// ---------------- variance hinge loss ----------------
__global__ __launch_bounds__(256) void k_vloss(const float* __restrict__ csum,
                                               const float* __restrict__ csumsq,
                                               float* __restrict__ scal) {
  int idx = blockIdx.x * 256 + threadIdx.x;  // < 1024
  float s = csum[idx], sq = csumsq[idx];
  float mean = s * (1.0f / (float)B_N);
  float var = (sq - (float)B_N * mean * mean) * (1.0f / (float)(B_N - 1));
  float term = fmaxf(0.f, 0.2f - sqrtf(var + 1e-8f));
  term = wred_sum(term);
  __shared__ float sw[4];
  if ((threadIdx.x & 63) == 0) sw[threadIdx.x >> 6] = term;
  __syncthreads();
  if (threadIdx.x == 0) atomicAdd(&scal[0], sw[0] + sw[1] + sw[2] + sw[3]);
}

// ---------------- gram (bf16 input, upper-triangle tiles, split-K 16) ----------------
__global__ __launch_bounds__(256) void k_gram(const u16* __restrict__ zb1,
                                              const u16* __restrict__ zb2,
                                              float* __restrict__ Gpart) {
  int zi = blockIdx.z >> 4, chunk = blockIdx.z & 15;
  const u16* z = zi ? zb2 : zb1;
  int ti = 0, xx = blockIdx.x;
  while (xx >= 8 - ti) { xx -= 8 - ti; ti++; }
  int tj = ti + xx;
  int i0 = ti * 64, j0 = tj * 64;
  __shared__ u16 lA[64][32], lB[64][32];
  int t = threadIdx.x, wid = t >> 6, lane = t & 63;
  int br = t & 31, fg = t >> 5;
  f32x4 acc[4];
#pragma unroll
  for (int q = 0; q < 4; q++) acc[q] = (f32x4){0.f, 0.f, 0.f, 0.f};
  for (int bb = 0; bb < 1024; bb += 32) {
    size_t rb = ((size_t)chunk * 1024 + bb + br) * D_N;
    bf16x8 va = *(const bf16x8*)&z[rb + i0 + fg * 8];
    bf16x8 vb = *(const bf16x8*)&z[rb + j0 + fg * 8];
#pragma unroll
    for (int e = 0; e < 8; e++) {
      lA[fg * 8 + e][br] = (u16)va[e];
      lB[fg * 8 + e][br] = (u16)vb[e];
    }
    __syncthreads();
    int m = lane & 15, q = lane >> 4;
    bf16x8 a = *(const bf16x8*)&lA[16 * wid + m][8 * q];
#pragma unroll
    for (int tt = 0; tt < 4; tt++) {
      bf16x8 b = *(const bf16x8*)&lB[16 * tt + m][8 * q];
      acc[tt] = __builtin_amdgcn_mfma_f32_16x16x32_bf16(a, b, acc[tt], 0, 0, 0);
    }
    __syncthreads();
  }
  float* gp = Gpart + (((size_t)zi * 16 + chunk) * 36 + blockIdx.x) * 4096;
  int n = lane & 15, q = lane >> 4;
#pragma unroll
  for (int tt = 0; tt < 4; tt++)
#pragma unroll
    for (int r = 0; r < 4; r++)
      gp[(16 * wid + q * 4 + r) * 64 + 16 * tt + n] = acc[tt][r];
}

// ---------------- covariance off-diag reduce (triangle, weighted) ----------------
__global__ __launch_bounds__(256) void k_covreduce(const float* __restrict__ Gpart,
                                                   const float* __restrict__ csum,
                                                   float* __restrict__ scal) {
  int zi = blockIdx.y;
  int tile = blockIdx.x >> 4, part = blockIdx.x & 15;
  int ti = 0, xx = tile;
  while (xx >= 8 - ti) { xx -= 8 - ti; ti++; }
  int tj = ti + xx;
  int idx = part * 256 + threadIdx.x;
  int li = idx >> 6, lj = idx & 63;
  int i = ti * 64 + li, j = tj * 64 + lj;
  float g = 0.f;
#pragma unroll
  for (int c = 0; c < 16; c++)
    g += Gpart[(((size_t)zi * 16 + c) * 36 + tile) * 4096 + idx];
  float mi = csum[zi * D_N + i] * (1.0f / (float)B_N);
  float mj = csum[zi * D_N + j] * (1.0f / (float)B_N);
  float C = (g - (float)B_N * mi * mj) * (1.0f / (float)(B_N - 1));
  float wgt = (ti == tj) ? ((li == lj) ? 0.f : 1.f) : 2.f;
  float v = wgt * C * C;
  v = wred_sum(v);
  __shared__ float sw[4];
  if ((threadIdx.x & 63) == 0) sw[threadIdx.x >> 6] = v;
  __syncthreads();
  if (threadIdx.x == 0) atomicAdd(&scal[1], sw[0] + sw[1] + sw[2] + sw[3]);
}

// ---------------- logits = zn @ W^T ----------------
// R10-exact structure (session best): 256x256 tile, BK=64, 8 waves, 128 KiB
// LDS double-buffer, counted vmcnt(8) deep pipeline (T3+T4), both-sides XOR
// swizzle (rule 21), setprio (T5), swapped MFMA operands, bx-major bijective
// XCD remap (verified FETCH 135->49 MB). R13: red-zero hoisted into kt=7's
// shadow (buf0 dead after kt=6's drain) -> one fewer epilogue barrier.
// NOTE (R11 lesson): acc[8][4] = 128 regs/thread in the unified VGPR/AGPR
// file; total ~252 -> 2 waves/SIMD is a HARD cap for this tile. Do not add
// a tighter __launch_bounds__ waves hint: (512,4) forces a 128-reg budget
// and spills the whole accumulator (measured 1.44 GB scratch writes, 4x).
__device__ __forceinline__ bf16x8 fragld(const u16* base, int row, int ks, int lane) {
  int seg = (ks * 4 + (lane >> 4)) ^ (row & 7);
  return *(const bf16x8*)&base[row * 64 + seg * 8];
}

__device__ __forceinline__ void stage256(const u16* __restrict__ G, int grow0,
                                         int d0, const u16* ldsbase, int t) {
#pragma unroll
  for (int q = 0; q < 4; q++) {
    int row = q * 64 + (t >> 3);
    int scol = ((t & 7) ^ ((t >> 3) & 7)) * 8;  // pre-swizzled global column
    gld16(G + (size_t)(grow0 + row) * D_N + d0 + scol,
          ldsbase + q * 4096 + (t >> 6) * 512);  // wave-uniform; HW adds lane*16
  }
}

__device__ __forceinline__ void comp256(const u16* tA, const u16* tB,
                                        f32x4 (&acc)[8][4], int wm, int wn, int lane) {
  bf16x8 bq[4][2];
#pragma unroll
  for (int j = 0; j < 4; j++)
#pragma unroll
    for (int ks = 0; ks < 2; ks++)
      bq[j][ks] = fragld(tB, wn * 64 + j * 16 + (lane & 15), ks, lane);
#pragma unroll
  for (int q = 0; q < 4; q++) {
    bf16x8 aq[2][2];
#pragma unroll
    for (int i2 = 0; i2 < 2; i2++)
#pragma unroll
      for (int ks = 0; ks < 2; ks++)
        aq[i2][ks] = fragld(tA, wm * 128 + (q * 2 + i2) * 16 + (lane & 15), ks, lane);
    __builtin_amdgcn_s_setprio(1);
#pragma unroll
    for (int i2 = 0; i2 < 2; i2++)
#pragma unroll
      for (int j = 0; j < 4; j++)
#pragma unroll
        for (int ks = 0; ks < 2; ks++)
          acc[q * 2 + i2][j] = __builtin_amdgcn_mfma_f32_16x16x32_bf16(
              bq[j][ks], aq[i2][ks], acc[q * 2 + i2][j], 0, 0, 0);
    __builtin_amdgcn_s_setprio(0);
  }
}

__global__ __launch_bounds__(512, 2) void k_logits(const u16* __restrict__ zn1,
                                                   const u16* __restrict__ zn2,
                                                   const u16* __restrict__ Wb,
                                                   u16* __restrict__ L1, u16* __restrict__ L2,
                                                   float* __restrict__ rowsum) {
  __shared__ u16 lds[65536];  // 128 KiB: [db][A|B][256][64]
  // bijective XCD remap (1024 blocks, 128/XCD) with BX-MAJOR decode:
  // 8 by-blocks per A-tile on one XCD -> A once from HBM, W once per XCD;
  // resident per-XCD working set = 4 A-tiles (1MB) + full W (2MB) < 4MB L2.
  int hw = blockIdx.x + 64 * (blockIdx.y + 8 * blockIdx.z);
  int l = (hw & 7) * 128 + (hw >> 3);
  int zi = l >> 9, bx = (l >> 3) & 63, by = l & 7;
  const u16* A = zi ? zn2 : zn1;
  u16* Lout = zi ? L2 : L1;
  int b0 = bx * 256, k0 = by * 256;
  int t = threadIdx.x, lane = t & 63, wid = t >> 6;
  int wm = wid >> 2, wn = wid & 3;  // 2 x 4 wave grid; per-wave 128(M) x 64(N)
  f32x4 acc[8][4];
#pragma unroll
  for (int i = 0; i < 8; i++)
#pragma unroll
    for (int j = 0; j < 4; j++) acc[i][j] = (f32x4){0.f, 0.f, 0.f, 0.f};

  // prologue: stage K-tiles 0 (buf0) and 1 (buf1); wait buf0 only
  stage256(A, b0, 0, lds, t);
  stage256(Wb, k0, 0, lds + 16384, t);
  stage256(A, b0, 64, lds + 32768, t);
  stage256(Wb, k0, 64, lds + 49152, t);
  asm volatile("s_waitcnt vmcnt(8)\n\ts_barrier" ::: "memory");

#pragma unroll
  for (int kt = 0; kt < 7; kt++) {
    const u16* tA = lds + (kt & 1) * 32768;
    comp256(tA, tA + 16384, acc, wm, wn, lane);
    if (kt < 6) {
      // all waves done reading buf(kt&1) -> safe to overwrite with kt+2
      asm volatile("s_barrier" ::: "memory");
      const u16* dst = lds + (kt & 1) * 32768;
      stage256(A, b0, (kt + 2) * 64, dst, t);
      stage256(Wb, k0, (kt + 2) * 64, dst + 16384, t);
      // wait kt+1's 8 loads (kt+2's 8 remain in flight across the barrier)
      asm volatile("s_waitcnt vmcnt(8)\n\ts_barrier" ::: "memory");
    } else {  // kt == 6: drain; buf0 dead after this barrier
      asm volatile("s_waitcnt vmcnt(0)\n\ts_barrier" ::: "memory");
    }
  }
  // zero the reduce scratch (lives in dead buf0) in the shadow of kt=7 compute
  float* red = (float*)lds;
  if (t < 256) red[t] = 0.f;
  comp256(lds + 32768, lds + 49152, acc, wm, wn, lane);  // kt = 7 (buf1)
  __syncthreads();

  // epilogue: packed bf16 stores (4 consecutive k per lane) + fused rs0
  int cb = lane & 15;   // b within 16-block
  int cq = lane >> 4;   // k quad
  float rp[16];
#pragma unroll
  for (int q = 0; q < 16; q++) rp[q] = 0.f;
#pragma unroll
  for (int i = 0; i < 8; i++)
#pragma unroll
    for (int j = 0; j < 4; j++) {
      f32x4 v = acc[i][j];
      u16x4 h = {f2bf(v[0]), f2bf(v[1]), f2bf(v[2]), f2bf(v[3])};
      int gb = b0 + wm * 128 + i * 16 + cb;
      int gk = k0 + wn * 64 + j * 16 + cq * 4;
      *(u16x4*)&Lout[(size_t)gb * K_N + gk] = h;
#pragma unroll
      for (int r = 0; r < 4; r++)
        rp[j * 4 + r] += __expf(20.0f * bf2f((short)h[r]));
    }
#pragma unroll
  for (int q = 0; q < 16; q++) {
#pragma unroll
    for (int o = 1; o < 16; o <<= 1) rp[q] += __shfl_xor(rp[q], o, 64);
  }
  if (cb == 0) {
#pragma unroll
    for (int j = 0; j < 4; j++)
#pragma unroll
      for (int r = 0; r < 4; r++)
        atomicAdd(&red[wn * 64 + j * 16 + cq * 4 + r], rp[j * 4 + r]);
  }
  __syncthreads();
  if (t < 256) atomicAdd(&rowsum[(size_t)zi * 3 * K_N + k0 + t], red[t]);
}

// ---------------- fused sinkhorn half-iteration pair ----------------
// c_it[b] = sum_k E[b,k]*r_it[k]  (in-wave), then rs_{it+1}[k] += E[b,k]/(B*c_it[b])
// pm permuted: phys(k) = (k&7)*256 + (k>>3) -> per-lane atomics lane-consecutive.
// Software-pipelined rows (R8, verified): double-buffered row loads issue row
// rr+1's loads BEFORE processing row rr; E recomputed to keep VGPRs ~110.
// R13: zero-visibility barrier moved to just before the pm atomics.
__global__ __launch_bounds__(256) void k_sink(const u16* __restrict__ L1,
                                              const u16* __restrict__ L2,
                                              float* __restrict__ rowsum, int it) {
  int zi = blockIdx.y;
  const u16* L = zi ? L2 : L1;
  const float* rs_in = rowsum + ((size_t)zi * 3 + it) * K_N;
  float* rs_out = rowsum + ((size_t)zi * 3 + it + 1) * K_N;
  __shared__ float pm[K_N];
  int t = threadIdx.x, lane = t & 63, wid = t >> 6;
  for (int k = t; k < K_N; k += 256) pm[k] = 0.f;
  float rv[32];
#pragma unroll
  for (int jj = 0; jj < 4; jj++) {
    const float4* p = (const float4*)&rs_in[jj * 512 + lane * 8];
    float4 x = p[0], y = p[1];
    rv[jj*8+0] = 1.0f / ((float)K_N * x.x); rv[jj*8+1] = 1.0f / ((float)K_N * x.y);
    rv[jj*8+2] = 1.0f / ((float)K_N * x.z); rv[jj*8+3] = 1.0f / ((float)K_N * x.w);
    rv[jj*8+4] = 1.0f / ((float)K_N * y.x); rv[jj*8+5] = 1.0f / ((float)K_N * y.y);
    rv[jj*8+6] = 1.0f / ((float)K_N * y.z); rv[jj*8+7] = 1.0f / ((float)K_N * y.w);
  }
  float racc[32];
#pragma unroll
  for (int q = 0; q < 32; q++) racc[q] = 0.f;
  int w = blockIdx.x * 4 + wid;  // 0..2047
  const u16* Lw = L + (size_t)w * 8 * K_N;
  bf16x8 bufA[4], bufB[4];
#pragma unroll
  for (int jj = 0; jj < 4; jj++)
    bufA[jj] = *(const bf16x8*)&Lw[jj * 512 + lane * 8];
#pragma unroll
  for (int rr = 0; rr < 8; rr++) {
    const bf16x8* cur = (rr & 1) ? bufB : bufA;
    bf16x8* nxt = (rr & 1) ? bufA : bufB;
    if (rr < 7) {
#pragma unroll
      for (int jj = 0; jj < 4; jj++)
        nxt[jj] = *(const bf16x8*)&Lw[(rr + 1) * K_N + jj * 512 + lane * 8];
    }
    float c = 0.f;
#pragma unroll
    for (int jj = 0; jj < 4; jj++)
#pragma unroll
      for (int e = 0; e < 8; e++)
        c += __expf(20.0f * bf2f(cur[jj][e])) * rv[jj * 8 + e];
#pragma unroll
    for (int o = 32; o; o >>= 1) c += __shfl_xor(c, o, 64);
    float cb = 1.0f / ((float)B_N * c);
#pragma unroll
    for (int jj = 0; jj < 4; jj++)
#pragma unroll
      for (int e = 0; e < 8; e++)
        racc[jj * 8 + e] += __expf(20.0f * bf2f(cur[jj][e])) * cb;
  }
  __syncthreads();  // all pm zeroing visible before any pm atomics
#pragma unroll
  for (int q = 0; q < 32; q++)
    atomicAdd(&pm[(q & 7) * 256 + (q >> 3) * 64 + lane], racc[q]);
  __syncthreads();
  for (int k = t; k < K_N; k += 256)
    atomicAdd(&rs_out[k], pm[(k & 7) * 256 + (k >> 3)]);
}

// ---------------- final fused pass: CE + diagnostics ----------------
// Round-9 team-split (verified: -30us): each ROW's K=2048 spans TWO waves
// (128 lanes, team = wave pair). Per-thread state halves -> ~120 VGPR, zero
// spill, grid 1024 = 4 waves/SIMD. Cross-wave combine via 320-B LDS exchange.
// R13: exchange barriers are raw lgkmcnt-only s_barrier (LDS-only exchange;
// __syncthreads would emit vmcnt(0) and stall all threads on lane0's
// fire-and-forget counts/scal atomics, 8x per block).
__global__ __launch_bounds__(256) void k_final(const u16* __restrict__ L1,
                                               const u16* __restrict__ L2,
                                               const float* __restrict__ rowsum,
                                               float* __restrict__ probsum,
                                               int* __restrict__ counts,
                                               float* __restrict__ scal) {
  __shared__ float pmerge[K_N];
  __shared__ float xw[4][20];  // per-wave totals: 12 f32 + 8 u32
  const float* rs1 = rowsum + 2 * K_N;
  const float* rs2 = rowsum + 5 * K_N;
  int t = threadIdx.x, lane = t & 63, wid = t >> 6;
  int half = wid & 1;            // which half of the team's 128 lanes
  int tl = half * 64 + lane;     // team-lane 0..127
  for (int k = t; k < K_N; k += 256) pmerge[k] = 0.f;
  float rv1[16], rv2[16];
#pragma unroll
  for (int jj = 0; jj < 2; jj++) {
    const float4* p1 = (const float4*)&rs1[jj * 1024 + tl * 8];
    const float4* p2 = (const float4*)&rs2[jj * 1024 + tl * 8];
    float4 x1 = p1[0], y1 = p1[1], x2 = p2[0], y2 = p2[1];
    rv1[jj*8+0] = 1.0f/((float)K_N*x1.x); rv1[jj*8+1] = 1.0f/((float)K_N*x1.y);
    rv1[jj*8+2] = 1.0f/((float)K_N*x1.z); rv1[jj*8+3] = 1.0f/((float)K_N*x1.w);
    rv1[jj*8+4] = 1.0f/((float)K_N*y1.x); rv1[jj*8+5] = 1.0f/((float)K_N*y1.y);
    rv1[jj*8+6] = 1.0f/((float)K_N*y1.z); rv1[jj*8+7] = 1.0f/((float)K_N*y1.w);
    rv2[jj*8+0] = 1.0f/((float)K_N*x2.x); rv2[jj*8+1] = 1.0f/((float)K_N*x2.y);
    rv2[jj*8+2] = 1.0f/((float)K_N*x2.z); rv2[jj*8+3] = 1.0f/((float)K_N*x2.w);
    rv2[jj*8+4] = 1.0f/((float)K_N*y2.x); rv2[jj*8+5] = 1.0f/((float)K_N*y2.y);
    rv2[jj*8+6] = 1.0f/((float)K_N*y2.z); rv2[jj*8+7] = 1.0f/((float)K_N*y2.w);
  }
  float pacc[16];
#pragma unroll
  for (int q = 0; q < 16; q++) pacc[q] = 0.f;
  float ce_acc = 0.f; int acc_cnt = 0;
  int w = blockIdx.x * 2 + (wid >> 1);  // team id 0..2047; 8 rows per team
  for (int pp = 0; pp < 4; pp++) {
    int ba = w * 8 + pp * 2;  // pair rows: ba, ba+1
    bf16x8 va1[2], va2[2], vb1[2], vb2[2];
#pragma unroll
    for (int jj = 0; jj < 2; jj++) {
      va1[jj] = *(const bf16x8*)&L1[(size_t)ba * K_N + jj * 1024 + tl * 8];
      va2[jj] = *(const bf16x8*)&L2[(size_t)ba * K_N + jj * 1024 + tl * 8];
      vb1[jj] = *(const bf16x8*)&L1[(size_t)(ba + 1) * K_N + jj * 1024 + tl * 8];
      vb2[jj] = *(const bf16x8*)&L2[(size_t)(ba + 1) * K_N + jj * 1024 + tl * 8];
    }
    float sE1a=0,sE2a=0,d12a=0,d21a=0,Z1a=0,Z2a=0;
    float sE1b=0,sE2b=0,d12b=0,d21b=0,Z1b=0,Z2b=0;
    unsigned um1a=0,um2a=0,ua1a=0,ua2a=0;
    unsigned um1b=0,um2b=0,ua1b=0,ua2b=0;
#pragma unroll
    for (int jj = 0; jj < 2; jj++)
#pragma unroll
      for (int e = 0; e < 8; e++) {
        int q = jj * 8 + e;
        unsigned ik = 2047u - (unsigned)(jj * 1024 + tl * 8 + e);
        float x1 = bf2f(va1[jj][e]), x2 = bf2f(va2[jj][e]);
        float t1 = __expf(10.0f * x1), t2 = __expf(10.0f * x2);
        float e1 = t1 * t1 * rv1[q], e2 = t2 * t2 * rv2[q];
        sE1a += e1; sE2a += e2; d12a += e1 * x2; d21a += e2 * x1; Z1a += t1; Z2a += t2;
        um1a = max(um1a, (fbits(t1) & 0xFFFFF800u) | ik);
        um2a = max(um2a, (fbits(t2) & 0xFFFFF800u) | ik);
        ua1a = max(ua1a, (fbits(e1) & 0xFFFFF800u) | ik);
        ua2a = max(ua2a, (fbits(e2) & 0xFFFFF800u) | ik);
        x1 = bf2f(vb1[jj][e]); x2 = bf2f(vb2[jj][e]);
        t1 = __expf(10.0f * x1); t2 = __expf(10.0f * x2);
        e1 = t1 * t1 * rv1[q]; e2 = t2 * t2 * rv2[q];
        sE1b += e1; sE2b += e2; d12b += e1 * x2; d21b += e2 * x1; Z1b += t1; Z2b += t2;
        um1b = max(um1b, (fbits(t1) & 0xFFFFF800u) | ik);
        um2b = max(um2b, (fbits(t2) & 0xFFFFF800u) | ik);
        ua1b = max(ua1b, (fbits(e1) & 0xFFFFF800u) | ik);
        ua2b = max(ua2b, (fbits(e2) & 0xFFFFF800u) | ik);
      }
#pragma unroll
    for (int o = 32; o; o >>= 1) {
      sE1a += __shfl_xor(sE1a, o, 64); sE2a += __shfl_xor(sE2a, o, 64);
      d12a += __shfl_xor(d12a, o, 64); d21a += __shfl_xor(d21a, o, 64);
      Z1a += __shfl_xor(Z1a, o, 64);   Z2a += __shfl_xor(Z2a, o, 64);
      sE1b += __shfl_xor(sE1b, o, 64); sE2b += __shfl_xor(sE2b, o, 64);
      d12b += __shfl_xor(d12b, o, 64); d21b += __shfl_xor(d21b, o, 64);
      Z1b += __shfl_xor(Z1b, o, 64);   Z2b += __shfl_xor(Z2b, o, 64);
      um1a = max(um1a, (unsigned)__shfl_xor((int)um1a, o, 64));
      um2a = max(um2a, (unsigned)__shfl_xor((int)um2a, o, 64));
      ua1a = max(ua1a, (unsigned)__shfl_xor((int)ua1a, o, 64));
      ua2a = max(ua2a, (unsigned)__shfl_xor((int)ua2a, o, 64));
      um1b = max(um1b, (unsigned)__shfl_xor((int)um1b, o, 64));
      um2b = max(um2b, (unsigned)__shfl_xor((int)um2b, o, 64));
      ua1b = max(ua1b, (unsigned)__shfl_xor((int)ua1b, o, 64));
      ua2b = max(ua2b, (unsigned)__shfl_xor((int)ua2b, o, 64));
    }
    // cross-wave (team) combine: publish wave totals, sync, merge partner's
    if (lane == 0) {
      float* xp = xw[wid];
      xp[0]=sE1a; xp[1]=sE2a; xp[2]=d12a; xp[3]=d21a; xp[4]=Z1a; xp[5]=Z2a;
      xp[6]=sE1b; xp[7]=sE2b; xp[8]=d12b; xp[9]=d21b; xp[10]=Z1b; xp[11]=Z2b;
      unsigned* xu = (unsigned*)(xp + 12);
      xu[0]=um1a; xu[1]=um2a; xu[2]=ua1a; xu[3]=ua2a;
      xu[4]=um1b; xu[5]=um2b; xu[6]=ua1b; xu[7]=ua2b;
    }
    asm volatile("s_waitcnt lgkmcnt(0)\n\ts_barrier" ::: "memory");
    {
      const float* xp = xw[wid ^ 1];
      sE1a+=xp[0]; sE2a+=xp[1]; d12a+=xp[2]; d21a+=xp[3]; Z1a+=xp[4]; Z2a+=xp[5];
      sE1b+=xp[6]; sE2b+=xp[7]; d12b+=xp[8]; d21b+=xp[9]; Z1b+=xp[10]; Z2b+=xp[11];
      const unsigned* xu = (const unsigned*)(xp + 12);
      um1a=max(um1a,xu[0]); um2a=max(um2a,xu[1]); ua1a=max(ua1a,xu[2]); ua2a=max(ua2a,xu[3]);
      um1b=max(um1b,xu[4]); um2b=max(um2b,xu[5]); ua1b=max(ua1b,xu[6]); ua2b=max(ua2b,xu[7]);
    }
    asm volatile("s_waitcnt lgkmcnt(0)\n\ts_barrier" ::: "memory");
    // row a epilogue (cs2 final colsum == sE; argmax(20x+log r) == argmax e)
    {
      int m1i = 2047 - (int)(um1a & 2047u), m2i = 2047 - (int)(um2a & 2047u);
      int a1i = 2047 - (int)(ua1a & 2047u), a2i = 2047 - (int)(ua2a & 2047u);
      float invc1 = 1.0f / sE1a, invc2 = 1.0f / sE2a;
      ce_acc += (10.0f * d12a) * invc1 - __logf(Z2a) + (10.0f * d21a) * invc2 - __logf(Z1a);
      acc_cnt += (m1i == a2i) + (m2i == a1i);
      if (lane == 0 && half == 0) { atomicAdd(&counts[m1i], 1); atomicAdd(&counts[m2i], 1); }
      float iZ1 = 1.0f / Z1a, iZ2 = 1.0f / Z2a;
#pragma unroll
      for (int jj = 0; jj < 2; jj++)
#pragma unroll
        for (int e = 0; e < 8; e++)
          pacc[jj * 8 + e] += __expf(10.0f * bf2f(va1[jj][e])) * iZ1
                            + __expf(10.0f * bf2f(va2[jj][e])) * iZ2;
    }
    // row b epilogue
    {
      int m1i = 2047 - (int)(um1b & 2047u), m2i = 2047 - (int)(um2b & 2047u);
      int a1i = 2047 - (int)(ua1b & 2047u), a2i = 2047 - (int)(ua2b & 2047u);
      float invc1 = 1.0f / sE1b, invc2 = 1.0f / sE2b;
      ce_acc += (10.0f * d12b) * invc1 - __logf(Z2b) + (10.0f * d21b) * invc2 - __logf(Z1b);
      acc_cnt += (m1i == a2i) + (m2i == a1i);
      if (lane == 0 && half == 0) { atomicAdd(&counts[m1i], 1); atomicAdd(&counts[m2i], 1); }
      float iZ1 = 1.0f / Z1b, iZ2 = 1.0f / Z2b;
#pragma unroll
      for (int jj = 0; jj < 2; jj++)
#pragma unroll
        for (int e = 0; e < 8; e++)
          pacc[jj * 8 + e] += __expf(10.0f * bf2f(vb1[jj][e])) * iZ1
                            + __expf(10.0f * bf2f(vb2[jj][e])) * iZ2;
    }
  }
  if (lane == 0 && half == 0) {
    atomicAdd(&scal[2], ce_acc);
    atomicAdd(&scal[3], (float)acc_cnt);
  }
  // team-lane-consecutive permuted merge (conflict-free): slot = e*256+jj*128+tl
  // (pp-loop barriers already made the pmerge zeroing globally visible)
#pragma unroll
  for (int jj = 0; jj < 2; jj++)
#pragma unroll
    for (int e = 0; e < 8; e++)
      atomicAdd(&pmerge[e * 256 + jj * 128 + tl], pacc[jj * 8 + e]);
  __syncthreads();
  // one global atomic per k per block; probsum in permuted slots (order-free sum)
  for (int k = t; k < K_N; k += 256) atomicAdd(&probsum[k], pmerge[k]);
}

// ---------------- combine: all 7 outputs ----------------
__global__ __launch_bounds__(256) void k_combine(const float* __restrict__ scal,
                                                 const float* __restrict__ probsum,
                                                 const int* __restrict__ counts,
                                                 float* __restrict__ out) {
  int t = threadIdx.x;
  float ec = 0.f, ep = 0.f;
  for (int k = t; k < K_N; k += 256) {
    float p = (float)counts[k] * (1.0f / (2.0f * (float)B_N));
    ec += -p * __logf(p + 1e-7f);
    float q = probsum[k] * (1.0f / (2.0f * (float)B_N));
    ep += -q * __logf(q + 1e-7f);
  }
  ec = wred_sum(ec);
  ep = wred_sum(ep);
  __shared__ float se[4], sp[4];
  if ((t & 63) == 0) { se[t >> 6] = ec; sp[t >> 6] = ep; }
  __syncthreads();
  if (t == 0) {
    float tec = se[0] + se[1] + se[2] + se[3];
    float tep = sp[0] + sp[1] + sp[2] + sp[3];
    float ce = -0.5f * scal[2] * (1.0f / (float)B_N);
    float lvar = scal[0] * (1.0f / (float)D_N);
    float lcov = scal[1] * (1.0f / (float)D_N);
    float acc = scal[3] * (1.0f / (2.0f * (float)B_N));
    out[0] = 15.0f * ce + lvar + lcov;
    out[1] = ce;
    out[2] = lvar;
    out[3] = lcov;
    out[4] = __expf(tec);
    out[5] = __expf(tep);
    out[6] = acc;
  }
}

extern "C" void kernel_launch(void* const* d_in, const int* in_sizes, int n_in,
                              void* d_out, int out_size, void* d_ws, size_t ws_size,
                              hipStream_t stream) {
  (void)in_sizes; (void)n_in; (void)out_size; (void)ws_size;
  const float* z1 = (const float*)d_in[0];
  const float* z2 = (const float*)d_in[1];
  const float* W = (const float*)d_in[2];

  char* w = (char*)d_ws;
  size_t off = 0;
  auto take = [&](size_t b) -> void* {
    void* p = w + off;
    off = (off + b + 255) & ~(size_t)255;
    return p;
  };
  float* rowsum = (float*)take(2 * 3 * K_N * 4);
  float* csum = (float*)take(2 * D_N * 4);
  float* csumsq = (float*)take(2 * D_N * 4);
  float* probsum = (float*)take(K_N * 4);
  int* counts = (int*)take(K_N * 4);
  float* scal = (float*)take(64);
  size_t zero_bytes = off;
  u16* zn1 = (u16*)take((size_t)B_N * D_N * 2);
  u16* zn2 = (u16*)take((size_t)B_N * D_N * 2);
  u16* Wb = (u16*)take((size_t)K_N * D_N * 2);
  u16* L1 = (u16*)take((size_t)B_N * K_N * 2);
  u16* L2 = (u16*)take((size_t)B_N * K_N * 2);
  float* Gpart = (float*)take((size_t)2 * 16 * 36 * 4096 * 4);
  // raw-bf16 z aliases the (not yet live) L1 buffer; gram/colstats finish before k_logits
  u16* zb1 = L1;
  u16* zb2 = L1 + (size_t)B_N * D_N;

  hipMemsetAsync(d_ws, 0, zero_bytes, stream);

  k_rownorm<<<8192, 256, 0, stream>>>(z1, z2, zn1, zn2, zb1, zb2);
  k_convW<<<512, 256, 0, stream>>>(W, Wb);
  k_colstats<<<dim3(1, 128, 2), dim3(64, 8), 0, stream>>>(zb1, zb2, csum, csumsq);
  k_vloss<<<4, 256, 0, stream>>>(csum, csumsq, scal);
  k_gram<<<dim3(36, 1, 32), 256, 0, stream>>>(zb1, zb2, Gpart);
  k_covreduce<<<dim3(36 * 16, 2), 256, 0, stream>>>(Gpart, csum, scal);
  k_logits<<<dim3(64, 8, 2), 512, 0, stream>>>(zn1, zn2, Wb, L1, L2, rowsum);
  k_sink<<<dim3(512, 2), 256, 0, stream>>>(L1, L2, rowsum, 0);
  k_sink<<<dim3(512, 2), 256, 0, stream>>>(L1, L2, rowsum, 1);
  k_final<<<1024, 256, 0, stream>>>(L1, L2, rowsum, probsum, counts, scal);
  k_combine<<<1, 256, 0, stream>>>(scal, probsum, counts, (float*)d_out);
}

// Round 14
// 504.477 us; speedup vs baseline: 1.0126x; 1.0126x over previous
//
#include <hip/hip_runtime.h>
#include <hip/hip_bf16.h>

#define B_N 16384
#define D_N 512
#define K_N 2048

typedef __attribute__((ext_vector_type(8))) short bf16x8;
typedef __attribute__((ext_vector_type(4))) float f32x4;
typedef __attribute__((ext_vector_type(4))) unsigned short u16x4;
typedef unsigned short u16;

__device__ __forceinline__ float bf2f(short s) {
  return __builtin_bit_cast(float, ((unsigned)(u16)s) << 16);
}
__device__ __forceinline__ u16 f2bf(float x) {
  return __builtin_bit_cast(u16, __float2bfloat16(x));
}
__device__ __forceinline__ unsigned fbits(float x) {
  return __builtin_bit_cast(unsigned, x);
}
__device__ __forceinline__ float wred_sum(float v) {
#pragma unroll
  for (int o = 32; o; o >>= 1) v += __shfl_down(v, o, 64);
  return v;
}

__device__ __forceinline__ void gld16(const u16* g, const u16* l) {
  __builtin_amdgcn_global_load_lds((const __attribute__((address_space(1))) void*)g,
                                   (__attribute__((address_space(3))) void*)l, 16, 0, 0);
}

// ---------------- row l2norm + bf16 convert (normalized + raw) ----------------
__global__ __launch_bounds__(256) void k_rownorm(const float* __restrict__ z1,
                                                 const float* __restrict__ z2,
                                                 u16* __restrict__ zn1, u16* __restrict__ zn2,
                                                 u16* __restrict__ zb1, u16* __restrict__ zb2) {
  int wid = threadIdx.x >> 6, lane = threadIdx.x & 63;
  int row = blockIdx.x * 4 + wid;
  const float* z; u16 *zn, *zb; int r;
  if (row < B_N) { z = z1; zn = zn1; zb = zb1; r = row; }
  else { z = z2; zn = zn2; zb = zb2; r = row - B_N; }
  const float4* zr = (const float4*)(z + (size_t)r * D_N);
  float4 va = zr[lane], vb = zr[lane + 64];
  float ss = va.x*va.x + va.y*va.y + va.z*va.z + va.w*va.w
           + vb.x*vb.x + vb.y*vb.y + vb.z*vb.z + vb.w*vb.w;
#pragma unroll
  for (int o = 32; o; o >>= 1) ss += __shfl_xor(ss, o, 64);
  float inv = 1.0f / fmaxf(sqrtf(ss), 1e-12f);
  u16x4 pa = {f2bf(va.x), f2bf(va.y), f2bf(va.z), f2bf(va.w)};
  u16x4 pb = {f2bf(vb.x), f2bf(vb.y), f2bf(vb.z), f2bf(vb.w)};
  u16x4 na = {f2bf(va.x*inv), f2bf(va.y*inv), f2bf(va.z*inv), f2bf(va.w*inv)};
  u16x4 nb = {f2bf(vb.x*inv), f2bf(vb.y*inv), f2bf(vb.z*inv), f2bf(vb.w*inv)};
  ((u16x4*)(zb + (size_t)r * D_N))[lane] = pa;
  ((u16x4*)(zb + (size_t)r * D_N))[lane + 64] = pb;
  ((u16x4*)(zn + (size_t)r * D_N))[lane] = na;
  ((u16x4*)(zn + (size_t)r * D_N))[lane + 64] = nb;
}

// ---------------- W -> bf16 ----------------
__global__ __launch_bounds__(256) void k_convW(const float* __restrict__ W,
                                               u16* __restrict__ Wb) {
  size_t base = ((size_t)blockIdx.x * 256 + threadIdx.x) * 8;
#pragma unroll
  for (int j = 0; j < 8; j++) Wb[base + j] = f2bf(W[base + j]);
}

// ---------------- per-column sum / sumsq (bf16 input) ----------------
__global__ __launch_bounds__(512) void k_colstats(const u16* __restrict__ zb1,
                                                  const u16* __restrict__ zb2,
                                                  float* __restrict__ csum,
                                                  float* __restrict__ csumsq) {
  int zi = blockIdx.z;
  const u16* z = zi ? zb2 : zb1;
  __shared__ float s1[512], s2[512];
  int t = threadIdx.y * 64 + threadIdx.x;
  s1[t] = 0.f; s2[t] = 0.f;
  __syncthreads();
  int c0 = threadIdx.x * 8;
  float a[8], a2[8];
#pragma unroll
  for (int e = 0; e < 8; e++) { a[e] = 0.f; a2[e] = 0.f; }
  for (int u = 0; u < 16; u++) {
    int r = blockIdx.y * 128 + threadIdx.y + 8 * u;
    bf16x8 v = *(const bf16x8*)&z[(size_t)r * D_N + c0];
#pragma unroll
    for (int e = 0; e < 8; e++) { float x = bf2f(v[e]); a[e] += x; a2[e] += x * x; }
  }
#pragma unroll
  for (int e = 0; e < 8; e++) {
    atomicAdd(&s1[c0 + e], a[e]);
    atomicAdd(&s2[c0 + e], a2[e]);
  }
  __syncthreads();
  atomicAdd(&csum[zi * D_N + t], s1[t]);
  atomicAdd(&csumsq[zi * D_N + t], s2[t]);
}

// ---------------- variance hinge loss ----------------
__global__ __launch_bounds__(256) void k_vloss(const float* __restrict__ csum,
                                               const float* __restrict__ csumsq,
                                               float* __restrict__ scal) {
  int idx = blockIdx.x * 256 + threadIdx.x;  // < 1024
  float s = csum[idx], sq = csumsq[idx];
  float mean = s * (1.0f / (float)B_N);
  float var = (sq - (float)B_N * mean * mean) * (1.0f / (float)(B_N - 1));
  float term = fmaxf(0.f, 0.2f - sqrtf(var + 1e-8f));
  term = wred_sum(term);
  __shared__ float sw[4];
  if ((threadIdx.x & 63) == 0) sw[threadIdx.x >> 6] = term;
  __syncthreads();
  if (threadIdx.x == 0) atomicAdd(&scal[0], sw[0] + sw[1] + sw[2] + sw[3]);
}

// ---------------- gram (bf16 input, upper-triangle tiles, split-K 16) ----------------
__global__ __launch_bounds__(256) void k_gram(const u16* __restrict__ zb1,
                                              const u16* __restrict__ zb2,
                                              float* __restrict__ Gpart) {
  int zi = blockIdx.z >> 4, chunk = blockIdx.z & 15;
  const u16* z = zi ? zb2 : zb1;
  int ti = 0, xx = blockIdx.x;
  while (xx >= 8 - ti) { xx -= 8 - ti; ti++; }
  int tj = ti + xx;
  int i0 = ti * 64, j0 = tj * 64;
  __shared__ u16 lA[64][32], lB[64][32];
  int t = threadIdx.x, wid = t >> 6, lane = t & 63;
  int br = t & 31, fg = t >> 5;
  f32x4 acc[4];
#pragma unroll
  for (int q = 0; q < 4; q++) acc[q] = (f32x4){0.f, 0.f, 0.f, 0.f};
  for (int bb = 0; bb < 1024; bb += 32) {
    size_t rb = ((size_t)chunk * 1024 + bb + br) * D_N;
    bf16x8 va = *(const bf16x8*)&z[rb + i0 + fg * 8];
    bf16x8 vb = *(const bf16x8*)&z[rb + j0 + fg * 8];
#pragma unroll
    for (int e = 0; e < 8; e++) {
      lA[fg * 8 + e][br] = (u16)va[e];
      lB[fg * 8 + e][br] = (u16)vb[e];
    }
    __syncthreads();
    int m = lane & 15, q = lane >> 4;
    bf16x8 a = *(const bf16x8*)&lA[16 * wid + m][8 * q];
#pragma unroll
    for (int tt = 0; tt < 4; tt++) {
      bf16x8 b = *(const bf16x8*)&lB[16 * tt + m][8 * q];
      acc[tt] = __builtin_amdgcn_mfma_f32_16x16x32_bf16(a, b, acc[tt], 0, 0, 0);
    }
    __syncthreads();
  }
  float* gp = Gpart + (((size_t)zi * 16 + chunk) * 36 + blockIdx.x) * 4096;
  int n = lane & 15, q = lane >> 4;
#pragma unroll
  for (int tt = 0; tt < 4; tt++)
#pragma unroll
    for (int r = 0; r < 4; r++)
      gp[(16 * wid + q * 4 + r) * 64 + 16 * tt + n] = acc[tt][r];
}

// ---------------- covariance off-diag reduce (triangle, weighted) ----------------
__global__ __launch_bounds__(256) void k_covreduce(const float* __restrict__ Gpart,
                                                   const float* __restrict__ csum,
                                                   float* __restrict__ scal) {
  int zi = blockIdx.y;
  int tile = blockIdx.x >> 4, part = blockIdx.x & 15;
  int ti = 0, xx = tile;
  while (xx >= 8 - ti) { xx -= 8 - ti; ti++; }
  int tj = ti + xx;
  int idx = part * 256 + threadIdx.x;
  int li = idx >> 6, lj = idx & 63;
  int i = ti * 64 + li, j = tj * 64 + lj;
  float g = 0.f;
#pragma unroll
  for (int c = 0; c < 16; c++)
    g += Gpart[(((size_t)zi * 16 + c) * 36 + tile) * 4096 + idx];
  float mi = csum[zi * D_N + i] * (1.0f / (float)B_N);
  float mj = csum[zi * D_N + j] * (1.0f / (float)B_N);
  float C = (g - (float)B_N * mi * mj) * (1.0f / (float)(B_N - 1));
  float wgt = (ti == tj) ? ((li == lj) ? 0.f : 1.f) : 2.f;
  float v = wgt * C * C;
  v = wred_sum(v);
  __shared__ float sw[4];
  if ((threadIdx.x & 63) == 0) sw[threadIdx.x >> 6] = v;
  __syncthreads();
  if (threadIdx.x == 0) atomicAdd(&scal[1], sw[0] + sw[1] + sw[2] + sw[3]);
}

// ---------------- logits = zn @ W^T ----------------
// R13-verified (101.4 us): 256x256 tile, BK=64, 8 waves, 128 KiB LDS
// double-buffer, counted vmcnt(8) deep pipeline (T3+T4), both-sides XOR
// swizzle (rule 21), setprio (T5), swapped MFMA operands, bx-major bijective
// XCD remap (verified FETCH 135->49 MB), red-zero hoisted into kt=7's shadow.
// NOTE (R11 lesson): acc[8][4] = 128 regs/thread in the unified VGPR/AGPR
// file; total ~250 -> 2 waves/SIMD is a HARD cap for this tile. Do not add
// a tighter __launch_bounds__ waves hint: (512,4) forces a 128-reg budget
// and spills the whole accumulator (measured 1.44 GB scratch writes, 4x).
__device__ __forceinline__ bf16x8 fragld(const u16* base, int row, int ks, int lane) {
  int seg = (ks * 4 + (lane >> 4)) ^ (row & 7);
  return *(const bf16x8*)&base[row * 64 + seg * 8];
}

__device__ __forceinline__ void stage256(const u16* __restrict__ G, int grow0,
                                         int d0, const u16* ldsbase, int t) {
#pragma unroll
  for (int q = 0; q < 4; q++) {
    int row = q * 64 + (t >> 3);
    int scol = ((t & 7) ^ ((t >> 3) & 7)) * 8;  // pre-swizzled global column
    gld16(G + (size_t)(grow0 + row) * D_N + d0 + scol,
          ldsbase + q * 4096 + (t >> 6) * 512);  // wave-uniform; HW adds lane*16
  }
}

__device__ __forceinline__ void comp256(const u16* tA, const u16* tB,
                                        f32x4 (&acc)[8][4], int wm, int wn, int lane) {
  bf16x8 bq[4][2];
#pragma unroll
  for (int j = 0; j < 4; j++)
#pragma unroll
    for (int ks = 0; ks < 2; ks++)
      bq[j][ks] = fragld(tB, wn * 64 + j * 16 + (lane & 15), ks, lane);
#pragma unroll
  for (int q = 0; q < 4; q++) {
    bf16x8 aq[2][2];
#pragma unroll
    for (int i2 = 0; i2 < 2; i2++)
#pragma unroll
      for (int ks = 0; ks < 2; ks++)
        aq[i2][ks] = fragld(tA, wm * 128 + (q * 2 + i2) * 16 + (lane & 15), ks, lane);
    __builtin_amdgcn_s_setprio(1);
#pragma unroll
    for (int i2 = 0; i2 < 2; i2++)
#pragma unroll
      for (int j = 0; j < 4; j++)
#pragma unroll
        for (int ks = 0; ks < 2; ks++)
          acc[q * 2 + i2][j] = __builtin_amdgcn_mfma_f32_16x16x32_bf16(
              bq[j][ks], aq[i2][ks], acc[q * 2 + i2][j], 0, 0, 0);
    __builtin_amdgcn_s_setprio(0);
  }
}

__global__ __launch_bounds__(512, 2) void k_logits(const u16* __restrict__ zn1,
                                                   const u16* __restrict__ zn2,
                                                   const u16* __restrict__ Wb,
                                                   u16* __restrict__ L1, u16* __restrict__ L2,
                                                   float* __restrict__ rowsum) {
  __shared__ u16 lds[65536];  // 128 KiB: [db][A|B][256][64]
  // bijective XCD remap (1024 blocks, 128/XCD) with BX-MAJOR decode:
  // 8 by-blocks per A-tile on one XCD -> A once from HBM, W once per XCD;
  // resident per-XCD working set = 4 A-tiles (1MB) + full W (2MB) < 4MB L2.
  int hw = blockIdx.x + 64 * (blockIdx.y + 8 * blockIdx.z);
  int l = (hw & 7) * 128 + (hw >> 3);
  int zi = l >> 9, bx = (l >> 3) & 63, by = l & 7;
  const u16* A = zi ? zn2 : zn1;
  u16* Lout = zi ? L2 : L1;
  int b0 = bx * 256, k0 = by * 256;
  int t = threadIdx.x, lane = t & 63, wid = t >> 6;
  int wm = wid >> 2, wn = wid & 3;  // 2 x 4 wave grid; per-wave 128(M) x 64(N)
  f32x4 acc[8][4];
#pragma unroll
  for (int i = 0; i < 8; i++)
#pragma unroll
    for (int j = 0; j < 4; j++) acc[i][j] = (f32x4){0.f, 0.f, 0.f, 0.f};

  // prologue: stage K-tiles 0 (buf0) and 1 (buf1); wait buf0 only
  stage256(A, b0, 0, lds, t);
  stage256(Wb, k0, 0, lds + 16384, t);
  stage256(A, b0, 64, lds + 32768, t);
  stage256(Wb, k0, 64, lds + 49152, t);
  asm volatile("s_waitcnt vmcnt(8)\n\ts_barrier" ::: "memory");

#pragma unroll
  for (int kt = 0; kt < 7; kt++) {
    const u16* tA = lds + (kt & 1) * 32768;
    comp256(tA, tA + 16384, acc, wm, wn, lane);
    if (kt < 6) {
      // all waves done reading buf(kt&1) -> safe to overwrite with kt+2
      asm volatile("s_barrier" ::: "memory");
      const u16* dst = lds + (kt & 1) * 32768;
      stage256(A, b0, (kt + 2) * 64, dst, t);
      stage256(Wb, k0, (kt + 2) * 64, dst + 16384, t);
      // wait kt+1's 8 loads (kt+2's 8 remain in flight across the barrier)
      asm volatile("s_waitcnt vmcnt(8)\n\ts_barrier" ::: "memory");
    } else {  // kt == 6: drain; buf0 dead after this barrier
      asm volatile("s_waitcnt vmcnt(0)\n\ts_barrier" ::: "memory");
    }
  }
  // zero the reduce scratch (lives in dead buf0) in the shadow of kt=7 compute
  float* red = (float*)lds;
  if (t < 256) red[t] = 0.f;
  comp256(lds + 32768, lds + 49152, acc, wm, wn, lane);  // kt = 7 (buf1)
  __syncthreads();

  // epilogue: packed bf16 stores (4 consecutive k per lane) + fused rs0
  int cb = lane & 15;   // b within 16-block
  int cq = lane >> 4;   // k quad
  float rp[16];
#pragma unroll
  for (int q = 0; q < 16; q++) rp[q] = 0.f;
#pragma unroll
  for (int i = 0; i < 8; i++)
#pragma unroll
    for (int j = 0; j < 4; j++) {
      f32x4 v = acc[i][j];
      u16x4 h = {f2bf(v[0]), f2bf(v[1]), f2bf(v[2]), f2bf(v[3])};
      int gb = b0 + wm * 128 + i * 16 + cb;
      int gk = k0 + wn * 64 + j * 16 + cq * 4;
      *(u16x4*)&Lout[(size_t)gb * K_N + gk] = h;
#pragma unroll
      for (int r = 0; r < 4; r++)
        rp[j * 4 + r] += __expf(20.0f * bf2f((short)h[r]));
    }
#pragma unroll
  for (int q = 0; q < 16; q++) {
#pragma unroll
    for (int o = 1; o < 16; o <<= 1) rp[q] += __shfl_xor(rp[q], o, 64);
  }
  if (cb == 0) {
#pragma unroll
    for (int j = 0; j < 4; j++)
#pragma unroll
      for (int r = 0; r < 4; r++)
        atomicAdd(&red[wn * 64 + j * 16 + cq * 4 + r], rp[j * 4 + r]);
  }
  __syncthreads();
  if (t < 256) atomicAdd(&rowsum[(size_t)zi * 3 * K_N + k0 + t], red[t]);
}

// ---------------- fused sinkhorn half-iteration pair ----------------
// R12-exact (session-best total). c_it[b] = sum_k E[b,k]*r_it[k] (in-wave),
// then rs_{it+1}[k] += E[b,k]/(B*c_it[b]). pm permuted: phys(k) =
// (k&7)*256+(k>>3) -> per-lane atomics lane-consecutive. Software-pipelined
// rows (R8): double-buffered row loads issue row rr+1's loads BEFORE
// processing row rr; E recomputed to keep VGPRs ~110.
__global__ __launch_bounds__(256) void k_sink(const u16* __restrict__ L1,
                                              const u16* __restrict__ L2,
                                              float* __restrict__ rowsum, int it) {
  int zi = blockIdx.y;
  const u16* L = zi ? L2 : L1;
  const float* rs_in = rowsum + ((size_t)zi * 3 + it) * K_N;
  float* rs_out = rowsum + ((size_t)zi * 3 + it + 1) * K_N;
  __shared__ float pm[K_N];
  int t = threadIdx.x, lane = t & 63, wid = t >> 6;
  for (int k = t; k < K_N; k += 256) pm[k] = 0.f;
  float rv[32];
#pragma unroll
  for (int jj = 0; jj < 4; jj++) {
    const float4* p = (const float4*)&rs_in[jj * 512 + lane * 8];
    float4 x = p[0], y = p[1];
    rv[jj*8+0] = 1.0f / ((float)K_N * x.x); rv[jj*8+1] = 1.0f / ((float)K_N * x.y);
    rv[jj*8+2] = 1.0f / ((float)K_N * x.z); rv[jj*8+3] = 1.0f / ((float)K_N * x.w);
    rv[jj*8+4] = 1.0f / ((float)K_N * y.x); rv[jj*8+5] = 1.0f / ((float)K_N * y.y);
    rv[jj*8+6] = 1.0f / ((float)K_N * y.z); rv[jj*8+7] = 1.0f / ((float)K_N * y.w);
  }
  __syncthreads();
  float racc[32];
#pragma unroll
  for (int q = 0; q < 32; q++) racc[q] = 0.f;
  int w = blockIdx.x * 4 + wid;  // 0..2047
  const u16* Lw = L + (size_t)w * 8 * K_N;
  bf16x8 bufA[4], bufB[4];
#pragma unroll
  for (int jj = 0; jj < 4; jj++)
    bufA[jj] = *(const bf16x8*)&Lw[jj * 512 + lane * 8];
#pragma unroll
  for (int rr = 0; rr < 8; rr++) {
    const bf16x8* cur = (rr & 1) ? bufB : bufA;
    bf16x8* nxt = (rr & 1) ? bufA : bufB;
    if (rr < 7) {
#pragma unroll
      for (int jj = 0; jj < 4; jj++)
        nxt[jj] = *(const bf16x8*)&Lw[(rr + 1) * K_N + jj * 512 + lane * 8];
    }
    float c = 0.f;
#pragma unroll
    for (int jj = 0; jj < 4; jj++)
#pragma unroll
      for (int e = 0; e < 8; e++)
        c += __expf(20.0f * bf2f(cur[jj][e])) * rv[jj * 8 + e];
#pragma unroll
    for (int o = 32; o; o >>= 1) c += __shfl_xor(c, o, 64);
    float cb = 1.0f / ((float)B_N * c);
#pragma unroll
    for (int jj = 0; jj < 4; jj++)
#pragma unroll
      for (int e = 0; e < 8; e++)
        racc[jj * 8 + e] += __expf(20.0f * bf2f(cur[jj][e])) * cb;
  }
#pragma unroll
  for (int q = 0; q < 32; q++)
    atomicAdd(&pm[(q & 7) * 256 + (q >> 3) * 64 + lane], racc[q]);
  __syncthreads();
  for (int k = t; k < K_N; k += 256)
    atomicAdd(&rs_out[k], pm[(k & 7) * 256 + (k >> 3)]);
}

// ---------------- final fused pass: CE + diagnostics ----------------
// R12-exact (session-best total). Round-9 team-split: each ROW's K=2048 spans
// TWO waves (128 lanes, team = wave pair). Per-thread state halves -> ~120
// VGPR, zero spill, grid 1024 = 4 waves/SIMD. Cross-wave combine via 320-B
// LDS exchange with __syncthreads (R13's lgkmcnt-only variant was neutral).
__global__ __launch_bounds__(256) void k_final(const u16* __restrict__ L1,
                                               const u16* __restrict__ L2,
                                               const float* __restrict__ rowsum,
                                               float* __restrict__ probsum,
                                               int* __restrict__ counts,
                                               float* __restrict__ scal) {
  __shared__ float pmerge[K_N];
  __shared__ float xw[4][20];  // per-wave totals: 12 f32 + 8 u32
  const float* rs1 = rowsum + 2 * K_N;
  const float* rs2 = rowsum + 5 * K_N;
  int t = threadIdx.x, lane = t & 63, wid = t >> 6;
  int half = wid & 1;            // which half of the team's 128 lanes
  int tl = half * 64 + lane;     // team-lane 0..127
  for (int k = t; k < K_N; k += 256) pmerge[k] = 0.f;
  float rv1[16], rv2[16];
#pragma unroll
  for (int jj = 0; jj < 2; jj++) {
    const float4* p1 = (const float4*)&rs1[jj * 1024 + tl * 8];
    const float4* p2 = (const float4*)&rs2[jj * 1024 + tl * 8];
    float4 x1 = p1[0], y1 = p1[1], x2 = p2[0], y2 = p2[1];
    rv1[jj*8+0] = 1.0f/((float)K_N*x1.x); rv1[jj*8+1] = 1.0f/((float)K_N*x1.y);
    rv1[jj*8+2] = 1.0f/((float)K_N*x1.z); rv1[jj*8+3] = 1.0f/((float)K_N*x1.w);
    rv1[jj*8+4] = 1.0f/((float)K_N*y1.x); rv1[jj*8+5] = 1.0f/((float)K_N*y1.y);
    rv1[jj*8+6] = 1.0f/((float)K_N*y1.z); rv1[jj*8+7] = 1.0f/((float)K_N*y1.w);
    rv2[jj*8+0] = 1.0f/((float)K_N*x2.x); rv2[jj*8+1] = 1.0f/((float)K_N*x2.y);
    rv2[jj*8+2] = 1.0f/((float)K_N*x2.z); rv2[jj*8+3] = 1.0f/((float)K_N*x2.w);
    rv2[jj*8+4] = 1.0f/((float)K_N*y2.x); rv2[jj*8+5] = 1.0f/((float)K_N*y2.y);
    rv2[jj*8+6] = 1.0f/((float)K_N*y2.z); rv2[jj*8+7] = 1.0f/((float)K_N*y2.w);
  }
  __syncthreads();
  float pacc[16];
#pragma unroll
  for (int q = 0; q < 16; q++) pacc[q] = 0.f;
  float ce_acc = 0.f; int acc_cnt = 0;
  int w = blockIdx.x * 2 + (wid >> 1);  // team id 0..2047; 8 rows per team
  for (int pp = 0; pp < 4; pp++) {
    int ba = w * 8 + pp * 2;  // pair rows: ba, ba+1
    bf16x8 va1[2], va2[2], vb1[2], vb2[2];
#pragma unroll
    for (int jj = 0; jj < 2; jj++) {
      va1[jj] = *(const bf16x8*)&L1[(size_t)ba * K_N + jj * 1024 + tl * 8];
      va2[jj] = *(const bf16x8*)&L2[(size_t)ba * K_N + jj * 1024 + tl * 8];
      vb1[jj] = *(const bf16x8*)&L1[(size_t)(ba + 1) * K_N + jj * 1024 + tl * 8];
      vb2[jj] = *(const bf16x8*)&L2[(size_t)(ba + 1) * K_N + jj * 1024 + tl * 8];
    }
    float sE1a=0,sE2a=0,d12a=0,d21a=0,Z1a=0,Z2a=0;
    float sE1b=0,sE2b=0,d12b=0,d21b=0,Z1b=0,Z2b=0;
    unsigned um1a=0,um2a=0,ua1a=0,ua2a=0;
    unsigned um1b=0,um2b=0,ua1b=0,ua2b=0;
#pragma unroll
    for (int jj = 0; jj < 2; jj++)
#pragma unroll
      for (int e = 0; e < 8; e++) {
        int q = jj * 8 + e;
        unsigned ik = 2047u - (unsigned)(jj * 1024 + tl * 8 + e);
        float x1 = bf2f(va1[jj][e]), x2 = bf2f(va2[jj][e]);
        float t1 = __expf(10.0f * x1), t2 = __expf(10.0f * x2);
        float e1 = t1 * t1 * rv1[q], e2 = t2 * t2 * rv2[q];
        sE1a += e1; sE2a += e2; d12a += e1 * x2; d21a += e2 * x1; Z1a += t1; Z2a += t2;
        um1a = max(um1a, (fbits(t1) & 0xFFFFF800u) | ik);
        um2a = max(um2a, (fbits(t2) & 0xFFFFF800u) | ik);
        ua1a = max(ua1a, (fbits(e1) & 0xFFFFF800u) | ik);
        ua2a = max(ua2a, (fbits(e2) & 0xFFFFF800u) | ik);
        x1 = bf2f(vb1[jj][e]); x2 = bf2f(vb2[jj][e]);
        t1 = __expf(10.0f * x1); t2 = __expf(10.0f * x2);
        e1 = t1 * t1 * rv1[q]; e2 = t2 * t2 * rv2[q];
        sE1b += e1; sE2b += e2; d12b += e1 * x2; d21b += e2 * x1; Z1b += t1; Z2b += t2;
        um1b = max(um1b, (fbits(t1) & 0xFFFFF800u) | ik);
        um2b = max(um2b, (fbits(t2) & 0xFFFFF800u) | ik);
        ua1b = max(ua1b, (fbits(e1) & 0xFFFFF800u) | ik);
        ua2b = max(ua2b, (fbits(e2) & 0xFFFFF800u) | ik);
      }
#pragma unroll
    for (int o = 32; o; o >>= 1) {
      sE1a += __shfl_xor(sE1a, o, 64); sE2a += __shfl_xor(sE2a, o, 64);
      d12a += __shfl_xor(d12a, o, 64); d21a += __shfl_xor(d21a, o, 64);
      Z1a += __shfl_xor(Z1a, o, 64);   Z2a += __shfl_xor(Z2a, o, 64);
      sE1b += __shfl_xor(sE1b, o, 64); sE2b += __shfl_xor(sE2b, o, 64);
      d12b += __shfl_xor(d12b, o, 64); d21b += __shfl_xor(d21b, o, 64);
      Z1b += __shfl_xor(Z1b, o, 64);   Z2b += __shfl_xor(Z2b, o, 64);
      um1a = max(um1a, (unsigned)__shfl_xor((int)um1a, o, 64));
      um2a = max(um2a, (unsigned)__shfl_xor((int)um2a, o, 64));
      ua1a = max(ua1a, (unsigned)__shfl_xor((int)ua1a, o, 64));
      ua2a = max(ua2a, (unsigned)__shfl_xor((int)ua2a, o, 64));
      um1b = max(um1b, (unsigned)__shfl_xor((int)um1b, o, 64));
      um2b = max(um2b, (unsigned)__shfl_xor((int)um2b, o, 64));
      ua1b = max(ua1b, (unsigned)__shfl_xor((int)ua1b, o, 64));
      ua2b = max(ua2b, (unsigned)__shfl_xor((int)ua2b, o, 64));
    }
    // cross-wave (team) combine: publish wave totals, sync, merge partner's
    if (lane == 0) {
      float* xp = xw[wid];
      xp[0]=sE1a; xp[1]=sE2a; xp[2]=d12a; xp[3]=d21a; xp[4]=Z1a; xp[5]=Z2a;
      xp[6]=sE1b; xp[7]=sE2b; xp[8]=d12b; xp[9]=d21b; xp[10]=Z1b; xp[11]=Z2b;
      unsigned* xu = (unsigned*)(xp + 12);
      xu[0]=um1a; xu[1]=um2a; xu[2]=ua1a; xu[3]=ua2a;
      xu[4]=um1b; xu[5]=um2b; xu[6]=ua1b; xu[7]=ua2b;
    }
    __syncthreads();
    {
      const float* xp = xw[wid ^ 1];
      sE1a+=xp[0]; sE2a+=xp[1]; d12a+=xp[2]; d21a+=xp[3]; Z1a+=xp[4]; Z2a+=xp[5];
      sE1b+=xp[6]; sE2b+=xp[7]; d12b+=xp[8]; d21b+=xp[9]; Z1b+=xp[10]; Z2b+=xp[11];
      const unsigned* xu = (const unsigned*)(xp + 12);
      um1a=max(um1a,xu[0]); um2a=max(um2a,xu[1]); ua1a=max(ua1a,xu[2]); ua2a=max(ua2a,xu[3]);
      um1b=max(um1b,xu[4]); um2b=max(um2b,xu[5]); ua1b=max(ua1b,xu[6]); ua2b=max(ua2b,xu[7]);
    }
    __syncthreads();
    // row a epilogue (cs2 final colsum == sE; argmax(20x+log r) == argmax e)
    {
      int m1i = 2047 - (int)(um1a & 2047u), m2i = 2047 - (int)(um2a & 2047u);
      int a1i = 2047 - (int)(ua1a & 2047u), a2i = 2047 - (int)(ua2a & 2047u);
      float invc1 = 1.0f / sE1a, invc2 = 1.0f / sE2a;
      ce_acc += (10.0f * d12a) * invc1 - __logf(Z2a) + (10.0f * d21a) * invc2 - __logf(Z1a);
      acc_cnt += (m1i == a2i) + (m2i == a1i);
      if (lane == 0 && half == 0) { atomicAdd(&counts[m1i], 1); atomicAdd(&counts[m2i], 1); }
      float iZ1 = 1.0f / Z1a, iZ2 = 1.0f / Z2a;
#pragma unroll
      for (int jj = 0; jj < 2; jj++)
#pragma unroll
        for (int e = 0; e < 8; e++)
          pacc[jj * 8 + e] += __expf(10.0f * bf2f(va1[jj][e])) * iZ1
                            + __expf(10.0f * bf2f(va2[jj][e])) * iZ2;
    }
    // row b epilogue
    {
      int m1i = 2047 - (int)(um1b & 2047u), m2i = 2047 - (int)(um2b & 2047u);
      int a1i = 2047 - (int)(ua1b & 2047u), a2i = 2047 - (int)(ua2b & 2047u);
      float invc1 = 1.0f / sE1b, invc2 = 1.0f / sE2b;
      ce_acc += (10.0f * d12b) * invc1 - __logf(Z2b) + (10.0f * d21b) * invc2 - __logf(Z1b);
      acc_cnt += (m1i == a2i) + (m2i == a1i);
      if (lane == 0 && half == 0) { atomicAdd(&counts[m1i], 1); atomicAdd(&counts[m2i], 1); }
      float iZ1 = 1.0f / Z1b, iZ2 = 1.0f / Z2b;
#pragma unroll
      for (int jj = 0; jj < 2; jj++)
#pragma unroll
        for (int e = 0; e < 8; e++)
          pacc[jj * 8 + e] += __expf(10.0f * bf2f(vb1[jj][e])) * iZ1
                            + __expf(10.0f * bf2f(vb2[jj][e])) * iZ2;
    }
  }
  if (lane == 0 && half == 0) {
    atomicAdd(&scal[2], ce_acc);
    atomicAdd(&scal[3], (float)acc_cnt);
  }
  // team-lane-consecutive permuted merge (conflict-free): slot = e*256+jj*128+tl
#pragma unroll
  for (int jj = 0; jj < 2; jj++)
#pragma unroll
    for (int e = 0; e < 8; e++)
      atomicAdd(&pmerge[e * 256 + jj * 128 + tl], pacc[jj * 8 + e]);
  __syncthreads();
  // one global atomic per k per block; probsum in permuted slots (order-free sum)
  for (int k = t; k < K_N; k += 256) atomicAdd(&probsum[k], pmerge[k]);
}

// ---------------- combine: all 7 outputs ----------------
__global__ __launch_bounds__(256) void k_combine(const float* __restrict__ scal,
                                                 const float* __restrict__ probsum,
                                                 const int* __restrict__ counts,
                                                 float* __restrict__ out) {
  int t = threadIdx.x;
  float ec = 0.f, ep = 0.f;
  for (int k = t; k < K_N; k += 256) {
    float p = (float)counts[k] * (1.0f / (2.0f * (float)B_N));
    ec += -p * __logf(p + 1e-7f);
    float q = probsum[k] * (1.0f / (2.0f * (float)B_N));
    ep += -q * __logf(q + 1e-7f);
  }
  ec = wred_sum(ec);
  ep = wred_sum(ep);
  __shared__ float se[4], sp[4];
  if ((t & 63) == 0) { se[t >> 6] = ec; sp[t >> 6] = ep; }
  __syncthreads();
  if (t == 0) {
    float tec = se[0] + se[1] + se[2] + se[3];
    float tep = sp[0] + sp[1] + sp[2] + sp[3];
    float ce = -0.5f * scal[2] * (1.0f / (float)B_N);
    float lvar = scal[0] * (1.0f / (float)D_N);
    float lcov = scal[1] * (1.0f / (float)D_N);
    float acc = scal[3] * (1.0f / (2.0f * (float)B_N));
    out[0] = 15.0f * ce + lvar + lcov;
    out[1] = ce;
    out[2] = lvar;
    out[3] = lcov;
    out[4] = __expf(tec);
    out[5] = __expf(tep);
    out[6] = acc;
  }
}

extern "C" void kernel_launch(void* const* d_in, const int* in_sizes, int n_in,
                              void* d_out, int out_size, void* d_ws, size_t ws_size,
                              hipStream_t stream) {
  (void)in_sizes; (void)n_in; (void)out_size; (void)ws_size;
  const float* z1 = (const float*)d_in[0];
  const float* z2 = (const float*)d_in[1];
  const float* W = (const float*)d_in[2];

  char* w = (char*)d_ws;
  size_t off = 0;
  auto take = [&](size_t b) -> void* {
    void* p = w + off;
    off = (off + b + 255) & ~(size_t)255;
    return p;
  };
  float* rowsum = (float*)take(2 * 3 * K_N * 4);
  float* csum = (float*)take(2 * D_N * 4);
  float* csumsq = (float*)take(2 * D_N * 4);
  float* probsum = (float*)take(K_N * 4);
  int* counts = (int*)take(K_N * 4);
  float* scal = (float*)take(64);
  size_t zero_bytes = off;
  u16* zn1 = (u16*)take((size_t)B_N * D_N * 2);
  u16* zn2 = (u16*)take((size_t)B_N * D_N * 2);
  u16* Wb = (u16*)take((size_t)K_N * D_N * 2);
  u16* L1 = (u16*)take((size_t)B_N * K_N * 2);
  u16* L2 = (u16*)take((size_t)B_N * K_N * 2);
  float* Gpart = (float*)take((size_t)2 * 16 * 36 * 4096 * 4);
  // raw-bf16 z aliases the (not yet live) L1 buffer; gram/colstats finish before k_logits
  u16* zb1 = L1;
  u16* zb2 = L1 + (size_t)B_N * D_N;

  hipMemsetAsync(d_ws, 0, zero_bytes, stream);

  k_rownorm<<<8192, 256, 0, stream>>>(z1, z2, zn1, zn2, zb1, zb2);
  k_convW<<<512, 256, 0, stream>>>(W, Wb);
  k_colstats<<<dim3(1, 128, 2), dim3(64, 8), 0, stream>>>(zb1, zb2, csum, csumsq);
  k_vloss<<<4, 256, 0, stream>>>(csum, csumsq, scal);
  k_gram<<<dim3(36, 1, 32), 256, 0, stream>>>(zb1, zb2, Gpart);
  k_covreduce<<<dim3(36 * 16, 2), 256, 0, stream>>>(Gpart, csum, scal);
  k_logits<<<dim3(64, 8, 2), 512, 0, stream>>>(zn1, zn2, Wb, L1, L2, rowsum);
  k_sink<<<dim3(512, 2), 256, 0, stream>>>(L1, L2, rowsum, 0);
  k_sink<<<dim3(512, 2), 256, 0, stream>>>(L1, L2, rowsum, 1);
  k_final<<<1024, 256, 0, stream>>>(L1, L2, rowsum, probsum, counts, scal);
  k_combine<<<1, 256, 0, stream>>>(scal, probsum, counts, (float*)d_out);
}